// Round 2
// baseline (432.586 us; speedup 1.0000x reference)
//
#include <hip/hip_runtime.h>
#include <cstdint>
#include <cstddef>

// ---------------------------------------------------------------------------
// COAMultiHeadAttention: MHA forward on gfx950.
//   B=2, T=2048, D=1024, H=16, HD=64.
//   Pipeline: dtype-detect -> 3x proj GEMM (Q,K,V) -> flash attention
//             -> output proj GEMM.
//   External float tensors may be f32 OR bf16 (runtime-detected); mask int32.
//   Internal ws tensors (Qp/Kp/Vp/att) are always bf16.
// ---------------------------------------------------------------------------

using frag8 = __attribute__((ext_vector_type(8))) short;   // 8 x bf16 (4 VGPRs)
using f32x4 = __attribute__((ext_vector_type(4))) float;   // MFMA accum
using int4v = __attribute__((ext_vector_type(4))) int;     // 16B load

#define MFMA16(a, b, c) __builtin_amdgcn_mfma_f32_16x16x32_bf16((a), (b), (c), 0, 0, 0)

__device__ __forceinline__ float bf2f(unsigned short s) {
    unsigned u = ((unsigned)s) << 16;
    return __builtin_bit_cast(float, u);
}
__device__ __forceinline__ short f2bf(float f) {
    unsigned u = __builtin_bit_cast(unsigned, f);
    u += 0x7fffu + ((u >> 16) & 1u);   // round-to-nearest-even
    return (short)(u >> 16);
}

// stage 8 f32 -> 8 bf16 -> one 16B LDS store
__device__ __forceinline__ void stage_cvt(short* dst, const float* src) {
    float4 lo = *(const float4*)src;
    float4 hi = *(const float4*)(src + 4);
    union { int4v v; short s[8]; } pk;
    pk.s[0] = f2bf(lo.x); pk.s[1] = f2bf(lo.y); pk.s[2] = f2bf(lo.z); pk.s[3] = f2bf(lo.w);
    pk.s[4] = f2bf(hi.x); pk.s[5] = f2bf(hi.y); pk.s[6] = f2bf(hi.z); pk.s[7] = f2bf(hi.w);
    *(int4v*)dst = pk.v;
}

// ---------------------------------------------------------------------------
// Dtype detection: if `query` is raw f32 read as uint16, its mantissa shorts
// have uniform-random bf16 exponent fields; bf16 N(0,1) data never exceeds
// exponent 0x82. One thread, 512 bytes.
// ---------------------------------------------------------------------------
__global__ void detect_dtype(const unsigned short* __restrict__ q, int* __restrict__ flag) {
    if (threadIdx.x == 0) {
        int f = 0;
        for (int i = 0; i < 256; ++i) {
            const int e = (q[i] >> 7) & 0xFF;
            f |= (e >= 0xC0) ? 1 : 0;
        }
        *flag = f;   // 1 => external floats are f32, 0 => bf16
    }
}

// ---------------------------------------------------------------------------
// GEMM: Y[M,N] = X[M,K] @ W[N,K]^T + bias[N], fp32 accum.
// 64x64 tile / 256 threads (4 waves, each 32x32 = 2x2 MFMA tiles).
// x_ext/y_ext: whether X / Y are external tensors (then dtype per *dflag);
// W and bias are always external. Internal tensors are bf16.
// ---------------------------------------------------------------------------
__global__ __launch_bounds__(256) void gemm_bt_bias(
    const void* __restrict__ X, const void* __restrict__ W,
    const void* __restrict__ bias, void* __restrict__ Y,
    int M, int N, int K, const int* __restrict__ dflag, int x_ext, int y_ext)
{
    __shared__ short sA[64][72];
    __shared__ short sB[64][72];

    const int isf32 = dflag[0];
    const bool xf = (x_ext != 0) && (isf32 != 0);
    const bool wf = (isf32 != 0);

    const int tid  = threadIdx.x;
    const int wave = tid >> 6;
    const int lane = tid & 63;
    const int g    = lane >> 4;    // quad group 0..3
    const int r    = lane & 15;
    const int m0   = blockIdx.y * 64;
    const int n0   = blockIdx.x * 64;
    const int wm   = (wave >> 1) * 32;
    const int wn   = (wave & 1) * 32;
    const int r0   = tid >> 3;         // staging row 0..31
    const int c0   = (tid & 7) * 8;    // staging col {0,8,...,56}

    f32x4 acc[2][2] = {};

    for (int k0 = 0; k0 < K; k0 += 64) {
        if (xf) {
            const float* Xf = (const float*)X;
            stage_cvt(&sA[r0][c0],      &Xf[(size_t)(m0 + r0) * K + k0 + c0]);
            stage_cvt(&sA[r0 + 32][c0], &Xf[(size_t)(m0 + r0 + 32) * K + k0 + c0]);
        } else {
            const unsigned short* Xb = (const unsigned short*)X;
            *(int4v*)&sA[r0][c0]      = *(const int4v*)&Xb[(size_t)(m0 + r0) * K + k0 + c0];
            *(int4v*)&sA[r0 + 32][c0] = *(const int4v*)&Xb[(size_t)(m0 + r0 + 32) * K + k0 + c0];
        }
        if (wf) {
            const float* Wf = (const float*)W;
            stage_cvt(&sB[r0][c0],      &Wf[(size_t)(n0 + r0) * K + k0 + c0]);
            stage_cvt(&sB[r0 + 32][c0], &Wf[(size_t)(n0 + r0 + 32) * K + k0 + c0]);
        } else {
            const unsigned short* Wb = (const unsigned short*)W;
            *(int4v*)&sB[r0][c0]      = *(const int4v*)&Wb[(size_t)(n0 + r0) * K + k0 + c0];
            *(int4v*)&sB[r0 + 32][c0] = *(const int4v*)&Wb[(size_t)(n0 + r0 + 32) * K + k0 + c0];
        }
        __syncthreads();
#pragma unroll
        for (int ks = 0; ks < 2; ++ks) {
            frag8 a0 = *(const frag8*)&sA[wm + r][ks * 32 + g * 8];
            frag8 a1 = *(const frag8*)&sA[wm + 16 + r][ks * 32 + g * 8];
            frag8 b0 = *(const frag8*)&sB[wn + r][ks * 32 + g * 8];
            frag8 b1 = *(const frag8*)&sB[wn + 16 + r][ks * 32 + g * 8];
            acc[0][0] = MFMA16(a0, b0, acc[0][0]);
            acc[0][1] = MFMA16(a0, b1, acc[0][1]);
            acc[1][0] = MFMA16(a1, b0, acc[1][0]);
            acc[1][1] = MFMA16(a1, b1, acc[1][1]);
        }
        __syncthreads();
    }

#pragma unroll
    for (int mt = 0; mt < 2; ++mt) {
#pragma unroll
        for (int nt = 0; nt < 2; ++nt) {
            const int n = n0 + wn + nt * 16 + r;
            const float bv = wf ? ((const float*)bias)[n]
                                : bf2f(((const unsigned short*)bias)[n]);
#pragma unroll
            for (int reg = 0; reg < 4; ++reg) {
                const int m = m0 + wm + mt * 16 + g * 4 + reg;  // C row=(lane>>4)*4+reg
                const float val = acc[mt][nt][reg] + bv;
                if (y_ext && isf32)
                    ((float*)Y)[(size_t)m * N + n] = val;
                else
                    ((unsigned short*)Y)[(size_t)m * N + n] = (unsigned short)f2bf(val);
            }
        }
    }
}

// ---------------------------------------------------------------------------
// Flash attention on bf16 ws tensors: one block per (b, h, 64-row Q tile);
// 4 waves x 16 q-rows. Online softmax (INF-free: init -1e30). P routed
// C-layout -> LDS -> A-layout; V transposed in LDS for contiguous B-frags.
// ---------------------------------------------------------------------------
#define T_SEQ 2048
#define D_MOD 1024

__global__ __launch_bounds__(256) void flash_attn(
    const unsigned short* __restrict__ Qp, const unsigned short* __restrict__ Kp,
    const unsigned short* __restrict__ Vp, const int* __restrict__ mask,
    unsigned short* __restrict__ att)
{
    __shared__ short sQ[64][72];
    __shared__ short sK[64][72];
    __shared__ short sVt[64][72];           // sVt[d][krow]
    __shared__ short sP[4][16][72];         // per-wave P scratch

    const int tid  = threadIdx.x;
    const int wave = tid >> 6;
    const int lane = tid & 63;
    const int g    = lane >> 4;
    const int r    = lane & 15;
    const int b    = blockIdx.z;
    const int h    = blockIdx.y;
    const int q0   = blockIdx.x * 64;
    const int r0   = tid >> 3;
    const int c0   = (tid & 7) * 8;

    const size_t base = ((size_t)b * T_SEQ) * D_MOD + (size_t)h * 64;

    *(int4v*)&sQ[r0][c0]      = *(const int4v*)&Qp[base + (size_t)(q0 + r0) * D_MOD + c0];
    *(int4v*)&sQ[r0 + 32][c0] = *(const int4v*)&Qp[base + (size_t)(q0 + r0 + 32) * D_MOD + c0];
    __syncthreads();

    frag8 aq0 = *(const frag8*)&sQ[wave * 16 + r][g * 8];
    frag8 aq1 = *(const frag8*)&sQ[wave * 16 + r][32 + g * 8];

    float run_m[4], run_l[4];
    f32x4 accO[4];
#pragma unroll
    for (int i = 0; i < 4; ++i) {
        run_m[i] = -1e30f;
        run_l[i] = 0.f;
        accO[i]  = f32x4{0.f, 0.f, 0.f, 0.f};
    }

    const float scale = 0.125f;  // 1/sqrt(64)
    const int* mrow = mask + ((size_t)b * T_SEQ) * T_SEQ;
    const int qrow = q0 + wave * 16;

    for (int kt = 0; kt < T_SEQ; kt += 64) {
        // ---- stage K tile + transposed V tile ----
        {
            *(int4v*)&sK[r0][c0]      = *(const int4v*)&Kp[base + (size_t)(kt + r0) * D_MOD + c0];
            *(int4v*)&sK[r0 + 32][c0] = *(const int4v*)&Kp[base + (size_t)(kt + r0 + 32) * D_MOD + c0];
            union { int4v v; short s[8]; } u0, u1;
            u0.v = *(const int4v*)&Vp[base + (size_t)(kt + r0) * D_MOD + c0];
            u1.v = *(const int4v*)&Vp[base + (size_t)(kt + r0 + 32) * D_MOD + c0];
#pragma unroll
            for (int j = 0; j < 8; ++j) {
                sVt[c0 + j][r0]      = u0.s[j];
                sVt[c0 + j][r0 + 32] = u1.s[j];
            }
        }
        __syncthreads();

        // ---- S = Q K^T (scaled): per wave 16 q-rows x 64 k-cols ----
        f32x4 s[4];
#pragma unroll
        for (int ct = 0; ct < 4; ++ct) {
            s[ct] = f32x4{0.f, 0.f, 0.f, 0.f};
            frag8 bk0 = *(const frag8*)&sK[ct * 16 + r][g * 8];
            frag8 bk1 = *(const frag8*)&sK[ct * 16 + r][32 + g * 8];
            s[ct] = MFMA16(aq0, bk0, s[ct]);
            s[ct] = MFMA16(aq1, bk1, s[ct]);
        }

        // ---- mask + scale + tile row-max ----
        float p[4][4];
        float tmax[4];
#pragma unroll
        for (int reg = 0; reg < 4; ++reg) tmax[reg] = -1e30f;
#pragma unroll
        for (int ct = 0; ct < 4; ++ct) {
#pragma unroll
            for (int reg = 0; reg < 4; ++reg) {
                float v = s[ct][reg] * scale;
                const int mk = mrow[(size_t)(qrow + g * 4 + reg) * T_SEQ + kt + ct * 16 + r];
                v = (mk == 0) ? -1e30f : v;
                p[ct][reg] = v;
                tmax[reg] = fmaxf(tmax[reg], v);
            }
        }
#pragma unroll
        for (int reg = 0; reg < 4; ++reg) {
            float t = tmax[reg];
            t = fmaxf(t, __shfl_xor(t, 1));
            t = fmaxf(t, __shfl_xor(t, 2));
            t = fmaxf(t, __shfl_xor(t, 4));
            t = fmaxf(t, __shfl_xor(t, 8));
            tmax[reg] = t;
        }

        // ---- online softmax update (all args finite) ----
        float alpha[4], rsum[4];
#pragma unroll
        for (int reg = 0; reg < 4; ++reg) {
            const float nm = fmaxf(run_m[reg], tmax[reg]);
            alpha[reg] = __expf(run_m[reg] - nm);
            run_m[reg] = nm;
            float srow = 0.f;
#pragma unroll
            for (int ct = 0; ct < 4; ++ct) {
                const float e = __expf(p[ct][reg] - nm);
                p[ct][reg] = e;
                srow += e;
            }
            rsum[reg] = srow;
        }
#pragma unroll
        for (int reg = 0; reg < 4; ++reg) {
            float t = rsum[reg];
            t += __shfl_xor(t, 1);
            t += __shfl_xor(t, 2);
            t += __shfl_xor(t, 4);
            t += __shfl_xor(t, 8);
            run_l[reg] = run_l[reg] * alpha[reg] + t;
        }

        // ---- P: C-layout regs -> LDS (bf16) ----
#pragma unroll
        for (int ct = 0; ct < 4; ++ct)
#pragma unroll
            for (int reg = 0; reg < 4; ++reg)
                sP[wave][g * 4 + reg][ct * 16 + r] = f2bf(p[ct][reg]);
        __syncthreads();

        // ---- O = alpha*O + P V ----
#pragma unroll
        for (int dt = 0; dt < 4; ++dt)
#pragma unroll
            for (int reg = 0; reg < 4; ++reg)
                accO[dt][reg] *= alpha[reg];

#pragma unroll
        for (int ks = 0; ks < 2; ++ks) {
            frag8 ap = *(const frag8*)&sP[wave][r][ks * 32 + g * 8];
#pragma unroll
            for (int dt = 0; dt < 4; ++dt) {
                frag8 bv = *(const frag8*)&sVt[dt * 16 + r][ks * 32 + g * 8];
                accO[dt] = MFMA16(ap, bv, accO[dt]);
            }
        }
        __syncthreads();  // protect sK/sVt/sP before next stage
    }

    // ---- epilogue: O / l, write att[b, q, h*64 + d] (bf16 ws) ----
#pragma unroll
    for (int dt = 0; dt < 4; ++dt) {
#pragma unroll
        for (int reg = 0; reg < 4; ++reg) {
            const float o = accO[dt][reg] / run_l[reg];
            const int qq = q0 + wave * 16 + g * 4 + reg;
            att[((size_t)b * T_SEQ + qq) * D_MOD + h * 64 + dt * 16 + r] =
                (unsigned short)f2bf(o);
        }
    }
}

// ---------------------------------------------------------------------------
extern "C" void kernel_launch(void* const* d_in, const int* in_sizes, int n_in,
                              void* d_out, int out_size, void* d_ws, size_t ws_size,
                              hipStream_t stream) {
    const void* query = d_in[0];
    const void* key   = d_in[1];
    const void* value = d_in[2];
    const int*  mask  = (const int*)d_in[3];
    const void* wq = d_in[4];
    const void* bq = d_in[5];
    const void* wk = d_in[6];
    const void* bk = d_in[7];
    const void* wv = d_in[8];
    const void* bv = d_in[9];
    const void* wo = d_in[10];
    const void* bo = d_in[11];

    const int Mtot = 2 * T_SEQ;   // 4096
    const int D = D_MOD;          // 1024

    unsigned short* Qp  = (unsigned short*)d_ws;
    unsigned short* Kp  = Qp + (size_t)Mtot * D;
    unsigned short* Vp  = Kp + (size_t)Mtot * D;
    unsigned short* att = Vp + (size_t)Mtot * D;
    int* flagp          = (int*)(att + (size_t)Mtot * D);

    const dim3 blk(256);
    const dim3 gg(D / 64, Mtot / 64);

    detect_dtype<<<1, 64, 0, stream>>>((const unsigned short*)query, flagp);

    gemm_bt_bias<<<gg, blk, 0, stream>>>(query, wq, bq, Qp, Mtot, D, D, flagp, 1, 0);
    gemm_bt_bias<<<gg, blk, 0, stream>>>(key,   wk, bk, Kp, Mtot, D, D, flagp, 1, 0);
    gemm_bt_bias<<<gg, blk, 0, stream>>>(value, wv, bv, Vp, Mtot, D, D, flagp, 1, 0);

    flash_attn<<<dim3(T_SEQ / 64, 16, 2), blk, 0, stream>>>(Qp, Kp, Vp, mask, att);

    gemm_bt_bias<<<gg, blk, 0, stream>>>(att, wo, bo, d_out, Mtot, D, D, flagp, 0, 1);
}